// Round 9
// baseline (73.257 us; speedup 1.0000x reference)
//
#include <hip/hip_runtime.h>
#include <math.h>

#define NPIX  6400
#define NH    8
#define KSPLIT 25
#define KPS   256         // keys per split (per block)
#define DITER 2           // 64-key iterations per wave (128 keys/wave)
#define LOG2E 1.4426950408889634f
#define DEFER_THR 11.5f   // log2-units (~8 nats)

typedef _Float16 f16x8 __attribute__((ext_vector_type(8)));
typedef __fp16   h16x2 __attribute__((ext_vector_type(2)));   // native cvt_pkrtz type
typedef __attribute__((ext_vector_type(16))) float f16v;
typedef __attribute__((ext_vector_type(4)))  float f4v;
typedef __attribute__((ext_vector_type(4)))  int   i4v;
typedef unsigned int u32x2 __attribute__((ext_vector_type(2)));

__device__ __forceinline__ f16v zero16() {
    f16v z = {0,0,0,0,0,0,0,0,0,0,0,0,0,0,0,0};
    return z;
}
__device__ __forceinline__ float exp2fast(float x) {
    float r;
    asm("v_exp_f32 %0, %1" : "=v"(r) : "v"(x));
    return r;
}
__device__ __forceinline__ unsigned pkrtz(float a, float b) {
    h16x2 h = __builtin_amdgcn_cvt_pkrtz(a, b);
    return __builtin_bit_cast(unsigned, h);
}
// both-halves exchange via permlane32_swap (VALU pipe, no LDS):
__device__ __forceinline__ float xhalf_max(float x) {
    unsigned a = __float_as_uint(x), b = a;
    u32x2 r = __builtin_amdgcn_permlane32_swap(a, b, false, false);
    return fmaxf(__uint_as_float(r[0]), __uint_as_float(r[1]));
}
__device__ __forceinline__ float xhalf_sum(float x) {
    unsigned a = __float_as_uint(x), b = a;
    u32x2 r = __builtin_amdgcn_permlane32_swap(a, b, false, false);
    return __uint_as_float(r[0]) + __uint_as_float(r[1]);
}
#define PL32SWAP(a, b) { u32x2 _r = __builtin_amdgcn_permlane32_swap((a), (b), false, false); (a) = _r[0]; (b) = _r[1]; }

// ---------------------------------------------------------------------------
// prep_fused (unchanged from round 8):
//  blocks 0..799  : Qs (head-summed, *log2e) and K -> fp16, stored [pixel][64f]
//  blocks 800..1199: V = WV_task*(conv3x3(X)+b)+BV_task -> fp16 [c][pixel]
// ---------------------------------------------------------------------------
__global__ __launch_bounds__(256)
void prep_fused(const float* __restrict__ X, const float* __restrict__ prevQ,
                const float* __restrict__ WQ_task, const float* __restrict__ BQ_task,
                const float* __restrict__ WQ_tm1, const float* __restrict__ WQ_x,
                const float* __restrict__ BQ,
                const float* __restrict__ WK_task, const float* __restrict__ BK_task,
                const float* __restrict__ WK_x, const float* __restrict__ BK,
                const float* __restrict__ Wc, const float* __restrict__ bc,
                const float* __restrict__ WV_task, const float* __restrict__ BV_task,
                _Float16* __restrict__ QG, _Float16* __restrict__ KG,
                _Float16* __restrict__ VG) {
    int bid = blockIdx.x;
    if (bid < 800) {
        int f0 = (bid / 25) * 2;                    // 0,2,..,62
        int p  = (bid % 25) * 256 + threadIdx.x;
        float qv[2], kv[2];
#pragma unroll
        for (int j = 0; j < 2; ++j) {
            int f = f0 + j;
            float x = X[f * NPIX + p];
            kv[j] = WK_task[f] * (WK_x[f] * x + BK[f]) + BK_task[f];
            float wqx_x = WQ_x[f] * x;
            float a = 0.f;
#pragma unroll
            for (int h = 0; h < NH; ++h) {
                int hf = h * 64 + f;
                float inner = WQ_tm1[hf] * prevQ[hf * NPIX + p] + wqx_x + BQ[hf];
                a += WQ_task[hf] * inner + BQ_task[hf];
            }
            qv[j] = a * LOG2E;                      // fold log2(e) for exp2 softmax
        }
        _Float16 q0 = (_Float16)qv[0], q1 = (_Float16)qv[1];
        _Float16 k0 = (_Float16)kv[0], k1 = (_Float16)kv[1];
        QG[p * 64 + f0] = q0; QG[p * 64 + f0 + 1] = q1;
        KG[p * 64 + f0] = k0; KG[p * 64 + f0 + 1] = k1;
    } else {
        int b2 = bid - 800;
        int c0 = (b2 / 25) * 2;                     // 0,2,..,30 (scalar)
        int p  = (b2 % 25) * 256 + threadIdx.x;
        int x0 = p / 80, y0 = p % 80;
        const float* wb0 = Wc + c0 * 576;
        const float* wb1 = Wc + (c0 + 1) * 576;
        float acc0 = 0.f, acc1 = 0.f;
        for (int dx = -1; dx <= 1; ++dx) {
            int xx = x0 + dx; if (xx < 0 || xx >= 80) continue;
            for (int dy = -1; dy <= 1; ++dy) {
                int yy = y0 + dy; if (yy < 0 || yy >= 80) continue;
                int pos = (dx + 1) * 3 + (dy + 1);
                const float* xp = X + xx * 80 + yy;
#pragma unroll 16
                for (int i = 0; i < 64; ++i) {
                    float xv = xp[i * NPIX];
                    acc0 = fmaf(xv, wb0[i * 9 + pos], acc0);
                    acc1 = fmaf(xv, wb1[i * 9 + pos], acc1);
                }
            }
        }
        VG[c0 * NPIX + p]       = (_Float16)(WV_task[c0] * (acc0 + bc[c0]) + BV_task[c0]);
        VG[(c0 + 1) * NPIX + p] = (_Float16)(WV_task[c0 + 1] * (acc1 + bc[c0 + 1]) + BV_task[c0 + 1]);
    }
}

// ---------------------------------------------------------------------------
// attn_mfma: LDS-free flash attention, fp16 32x32x16 MFMA, fine key-split for
// occupancy: 2-wave blocks (128 thr), 128 keys/wave, grid 200 q-tiles x 25
// key-splits = 5000 blocks -> ~4+ waves/SIMD resident (vs 3.9 grid-capped).
// exp2-direct softmax, defer-max, permlane32_swap P redistribution.
// ---------------------------------------------------------------------------
__global__ __launch_bounds__(128, 4)
void attn_mfma(const _Float16* __restrict__ QG,
               const _Float16* __restrict__ KG,
               const _Float16* __restrict__ VG,
               float* __restrict__ PmG, float* __restrict__ PlG,
               _Float16* __restrict__ PaccG) {
    __shared__ __align__(16) char lds[8704];   // macc 8192 | mm 256 | ll 256

    const int tid = threadIdx.x;
    const int w = tid >> 6, l = tid & 63;
    const int lq = l & 31, h = l >> 5;
    const int qt = blockIdx.x / KSPLIT, ks = blockIdx.x % KSPLIT;
    const int qbase = qt * 32;
    const int wkbase = ks * KPS + w * 128;

    // Q fragments (B-operand): col=q=lane&31, k=f=(chunk*16 + h*8 + j)
    f16x8 qf[4];
    {
        const _Float16* qp = QG + (qbase + lq) * 64 + h * 8;
#pragma unroll
        for (int c = 0; c < 4; ++c) qf[c] = *(const f16x8*)(qp + c * 16);
    }

    const _Float16* kg = KG + (wkbase + lq) * 64 + h * 8;
    const _Float16* vg = VG + lq * NPIX + wkbase + h * 8;

    f16v o = zero16();
    float m = -INFINITY, lsum = 0.f;

#pragma unroll
    for (int it = 0; it < DITER; ++it) {
        // ---- loads: tiles A (keys +0..31) and B (keys +32..63) ----
        f16x8 kA0 = *(const f16x8*)(kg +  0);
        f16x8 kA1 = *(const f16x8*)(kg + 16);
        f16x8 kA2 = *(const f16x8*)(kg + 32);
        f16x8 kA3 = *(const f16x8*)(kg + 48);
        f16x8 kB0 = *(const f16x8*)(kg + 2048);
        f16x8 kB1 = *(const f16x8*)(kg + 2064);
        f16x8 kB2 = *(const f16x8*)(kg + 2080);
        f16x8 kB3 = *(const f16x8*)(kg + 2096);
        f16x8 vA0 = *(const f16x8*)(vg +  0);
        f16x8 vA1 = *(const f16x8*)(vg + 16);
        f16x8 vB0 = *(const f16x8*)(vg + 32);
        f16x8 vB1 = *(const f16x8*)(vg + 48);
        kg += 4096; vg += 64;

        // ---- QK^T (swapped): s[k][q], two independent 4-MFMA chains ----
        f16v sA = zero16(), sB = zero16();
        sA = __builtin_amdgcn_mfma_f32_32x32x16_f16(kA0, qf[0], sA, 0, 0, 0);
        sB = __builtin_amdgcn_mfma_f32_32x32x16_f16(kB0, qf[0], sB, 0, 0, 0);
        sA = __builtin_amdgcn_mfma_f32_32x32x16_f16(kA1, qf[1], sA, 0, 0, 0);
        sB = __builtin_amdgcn_mfma_f32_32x32x16_f16(kB1, qf[1], sB, 0, 0, 0);
        sA = __builtin_amdgcn_mfma_f32_32x32x16_f16(kA2, qf[2], sA, 0, 0, 0);
        sB = __builtin_amdgcn_mfma_f32_32x32x16_f16(kB2, qf[2], sB, 0, 0, 0);
        sA = __builtin_amdgcn_mfma_f32_32x32x16_f16(kA3, qf[3], sA, 0, 0, 0);
        sB = __builtin_amdgcn_mfma_f32_32x32x16_f16(kB3, qf[3], sB, 0, 0, 0);

        // ---- joint online softmax over 64 keys (log2 units) ----
        float t8[8];
#pragma unroll
        for (int r = 0; r < 8; ++r)
            t8[r] = fmaxf(fmaxf(sA[2 * r], sA[2 * r + 1]),
                          fmaxf(sB[2 * r], sB[2 * r + 1]));
        float mx = fmaxf(fmaxf(fmaxf(t8[0], t8[1]), fmaxf(t8[2], t8[3])),
                         fmaxf(fmaxf(t8[4], t8[5]), fmaxf(t8[6], t8[7])));
        mx = xhalf_max(mx);
        if (__any(mx > m + DEFER_THR)) {            // defer-max: rescale rarely
            float mn = fmaxf(m, mx);
            float sc = exp2fast(m - mn);
            lsum *= sc;
#pragma unroll
            for (int r = 0; r < 16; ++r) o[r] *= sc;
            m = mn;
        }
        // P = exp2(s - m), stored back in sA/sB (register reuse)
#pragma unroll
        for (int r = 0; r < 16; ++r) sA[r] = exp2fast(sA[r] - m);
#pragma unroll
        for (int r = 0; r < 16; ++r) sB[r] = exp2fast(sB[r] - m);
        float ps = 0.f;
#pragma unroll
        for (int r = 0; r < 16; ++r) ps += sA[r] + sB[r];
        lsum += xhalf_sum(ps);

        // ---- pack P->fp16 pairs; permlane32_swap builds both B-frag regs ----
        {
            unsigned p0 = pkrtz(sA[0],  sA[1]),  p1 = pkrtz(sA[2],  sA[3]);
            unsigned p2 = pkrtz(sA[4],  sA[5]),  p3 = pkrtz(sA[6],  sA[7]);
            unsigned p4 = pkrtz(sA[8],  sA[9]),  p5 = pkrtz(sA[10], sA[11]);
            unsigned p6 = pkrtz(sA[12], sA[13]), p7 = pkrtz(sA[14], sA[15]);
            PL32SWAP(p0, p2); PL32SWAP(p1, p3); PL32SWAP(p4, p6); PL32SWAP(p5, p7);
            i4v f0 = { (int)p0, (int)p1, (int)p2, (int)p3 };
            i4v f1 = { (int)p4, (int)p5, (int)p6, (int)p7 };
            o = __builtin_amdgcn_mfma_f32_32x32x16_f16(vA0, __builtin_bit_cast(f16x8, f0), o, 0, 0, 0);
            o = __builtin_amdgcn_mfma_f32_32x32x16_f16(vA1, __builtin_bit_cast(f16x8, f1), o, 0, 0, 0);
        }
        {
            unsigned p0 = pkrtz(sB[0],  sB[1]),  p1 = pkrtz(sB[2],  sB[3]);
            unsigned p2 = pkrtz(sB[4],  sB[5]),  p3 = pkrtz(sB[6],  sB[7]);
            unsigned p4 = pkrtz(sB[8],  sB[9]),  p5 = pkrtz(sB[10], sB[11]);
            unsigned p6 = pkrtz(sB[12], sB[13]), p7 = pkrtz(sB[14], sB[15]);
            PL32SWAP(p0, p2); PL32SWAP(p1, p3); PL32SWAP(p4, p6); PL32SWAP(p5, p7);
            i4v f0 = { (int)p0, (int)p1, (int)p2, (int)p3 };
            i4v f1 = { (int)p4, (int)p5, (int)p6, (int)p7 };
            o = __builtin_amdgcn_mfma_f32_32x32x16_f16(vB0, __builtin_bit_cast(f16x8, f0), o, 0, 0, 0);
            o = __builtin_amdgcn_mfma_f32_32x32x16_f16(vB1, __builtin_bit_cast(f16x8, f1), o, 0, 0, 0);
        }
    }

    // ---- 2-wave merge via LDS ----
    float* mm = (float*)(lds + 8192);
    float* ll = (float*)(lds + 8448);
#pragma unroll
    for (int rg = 0; rg < 4; ++rg) {
        f4v val = { o[rg * 4 + 0], o[rg * 4 + 1], o[rg * 4 + 2], o[rg * 4 + 3] };
        int cb = rg * 8 + 4 * h;                              // channel base
        int byte = (w * 32 + lq) * 128 + ((cb * 4) ^ ((lq & 7) << 4));
        *(f4v*)(lds + byte) = val;
    }
    if (l < 32) { mm[w * 32 + lq] = m; ll[w * 32 + lq] = lsum; }
    __syncthreads();

    {
        int q = tid >> 2, cb = (tid & 3) * 8;                 // 8 channels/thread
        float m0 = mm[q], m1 = mm[32 + q];
        float M = fmaxf(m0, m1);
        float e0 = exp2fast(m0 - M), e1 = exp2fast(m1 - M);
        float L = ll[q] * e0 + ll[32 + q] * e1;
        float rL = 1.f / L;
        int swz = (q & 7) << 4;
        f4v a00 = *(f4v*)(lds + (0 * 32 + q) * 128 + ((cb * 4) ^ swz));
        f4v a01 = *(f4v*)(lds + (0 * 32 + q) * 128 + (((cb * 4) + 16) ^ swz));
        f4v a10 = *(f4v*)(lds + (1 * 32 + q) * 128 + ((cb * 4) ^ swz));
        f4v a11 = *(f4v*)(lds + (1 * 32 + q) * 128 + (((cb * 4) + 16) ^ swz));
        int qg = qbase + q;
        f16x8 outp;    // store NORMALIZED partial (A/L): fp16-safe magnitude
#pragma unroll
        for (int j = 0; j < 4; ++j) {
            outp[j]     = (_Float16)((a00[j] * e0 + a10[j] * e1) * rL);
            outp[4 + j] = (_Float16)((a01[j] * e0 + a11[j] * e1) * rL);
        }
        *(f16x8*)(PaccG + ks * 204800 + qg * 32 + cb) = outp;
        if ((tid & 3) == 0) { PmG[ks * NPIX + qg] = M; PlG[ks * NPIX + qg] = L; }
    }
}

// ---------------------------------------------------------------------------
// merge_out: combine the 25 per-split normalized partials, weights L*exp2(m-M)
// ---------------------------------------------------------------------------
__global__ __launch_bounds__(256)
void merge_out(const float* __restrict__ Pm, const float* __restrict__ Pl,
               const _Float16* __restrict__ Pacc, float* __restrict__ out) {
    int idx = blockIdx.x * 256 + threadIdx.x;       // < 204800
    int q = idx >> 5, c = idx & 31;
    float M = -INFINITY;
#pragma unroll
    for (int ksi = 0; ksi < KSPLIT; ++ksi) M = fmaxf(M, Pm[ksi * NPIX + q]);
    float den = 0.f, num = 0.f;
#pragma unroll
    for (int ksi = 0; ksi < KSPLIT; ++ksi) {
        float wgt = Pl[ksi * NPIX + q] * exp2fast(Pm[ksi * NPIX + q] - M);
        den += wgt;
        num += (float)Pacc[ksi * 204800 + q * 32 + c] * wgt;
    }
    out[c * NPIX + q] = num / den;
}

// ---------------------------------------------------------------------------
extern "C" void kernel_launch(void* const* d_in, const int* in_sizes, int n_in,
                              void* d_out, int out_size, void* d_ws, size_t ws_size,
                              hipStream_t stream) {
    const float* X       = (const float*)d_in[0];
    const float* WQ_task = (const float*)d_in[1];
    const float* BQ_task = (const float*)d_in[2];
    const float* WK_task = (const float*)d_in[3];
    const float* BK_task = (const float*)d_in[4];
    const float* WV_task = (const float*)d_in[5];
    const float* BV_task = (const float*)d_in[6];
    const float* WQ_tm1  = (const float*)d_in[7];
    const float* WQ_x    = (const float*)d_in[8];
    const float* BQ      = (const float*)d_in[9];
    const float* WK_x    = (const float*)d_in[10];
    const float* BK      = (const float*)d_in[11];
    const float* prev_Q  = (const float*)d_in[12];
    const float* Vconv_w = (const float*)d_in[13];
    const float* Vconv_b = (const float*)d_in[14];

    char* wsb = (char*)d_ws;
    _Float16* QG   = (_Float16*)(wsb + 0);         //   819200
    _Float16* KG   = (_Float16*)(wsb + 819200);    //   819200
    _Float16* VG   = (_Float16*)(wsb + 1638400);   //   409600
    float*    PmG  = (float*)(wsb + 2048000);      //   640000 (25*6400*4)
    float*    PlG  = (float*)(wsb + 2688000);      //   640000
    _Float16* PaccG= (_Float16*)(wsb + 3328000);   // 10240000 -> 13568000 total

    prep_fused<<<1200, 256, 0, stream>>>(X, prev_Q, WQ_task, BQ_task, WQ_tm1, WQ_x, BQ,
                                         WK_task, BK_task, WK_x, BK,
                                         Vconv_w, Vconv_b, WV_task, BV_task,
                                         QG, KG, VG);
    attn_mfma<<<200 * KSPLIT, 128, 0, stream>>>(QG, KG, VG, PmG, PlG, PaccG);
    merge_out<<<800, 256, 0, stream>>>(PmG, PlG, PaccG, (float*)d_out);
}